// Round 9
// baseline (283.063 us; speedup 1.0000x reference)
//
#include <hip/hip_runtime.h>
#include <hip/hip_bf16.h>

#define NB 256   // nodes
#define HH 64    // hidden

using short8 = __attribute__((ext_vector_type(8))) short;
using f4     = __attribute__((ext_vector_type(4))) float;

static __device__ __forceinline__ unsigned short f2bfbits(float f) {
    __hip_bfloat16 h = __float2bfloat16(f);
    return __builtin_bit_cast(unsigned short, h);
}
static __device__ __forceinline__ float bfbits2f(unsigned short u) {
    unsigned int x = (unsigned int)u << 16;
    return __builtin_bit_cast(float, x);
}

// split 8 f32 -> hi (RNE bf16) + lo (RNE residual bf16); v ~= hi + lo (~2^-17)
static __device__ __forceinline__ void split8(const float* v, short8& hi, short8& lo) {
    unsigned int hd[4], ld[4];
    #pragma unroll
    for (int j = 0; j < 4; ++j) {
        unsigned short h0 = f2bfbits(v[2*j]);
        unsigned short h1 = f2bfbits(v[2*j+1]);
        hd[j] = ((unsigned int)h1 << 16) | (unsigned int)h0;
        float r0 = v[2*j]   - bfbits2f(h0);
        float r1 = v[2*j+1] - bfbits2f(h1);
        ld[j] = ((unsigned int)f2bfbits(r1) << 16) | (unsigned int)f2bfbits(r0);
    }
    uint4 h4; h4.x = hd[0]; h4.y = hd[1]; h4.z = hd[2]; h4.w = hd[3];
    uint4 l4; l4.x = ld[0]; l4.y = ld[1]; l4.z = ld[2]; l4.w = ld[3];
    hi = __builtin_bit_cast(short8, h4);
    lo = __builtin_bit_cast(short8, l4);
}

// ---- prep (layer 0 only): per-row s, Xj, Xres from X; BUILD blocks also
//      make the W4 fragment tables, colsum(W4[1]) and colsum(W3[1]). ----
__global__ __launch_bounds__(256)
void prep_kernel(const float* __restrict__ Xsrc,
                 const float* __restrict__ W3l,
                 const float* __restrict__ W5l,
                 const float* __restrict__ W6l,
                 const float* __restrict__ W4all,
                 uint4* __restrict__ w4tab,
                 float* __restrict__ w41cs,
                 const float* __restrict__ W3l1,
                 float* __restrict__ w3cs,
                 float* __restrict__ s_ws,
                 float* __restrict__ Xjf,
                 float* __restrict__ Xres_ws)
{
    __shared__ float w5s[64*65];
    __shared__ float w6s[64*65];
    __shared__ float csl[4][64];
    __shared__ float cst[64];
    const int t = threadIdx.x;
    const int w = t >> 6, lane = t & 63;

    if (blockIdx.x >= 512) {
        const int l = blockIdx.x - 512;
        const float* W4l = W4all + (size_t)l * 4096;
        uint4* tab = w4tab + (size_t)l * 1024;
        const int mt = w, m = lane & 15, q = lane >> 4;
        const float* row = W4l + (size_t)(mt*16 + m) * 64;
        #pragma unroll
        for (int ks = 0; ks < 2; ++ks) {
            float v[8];
            *reinterpret_cast<float4*>(&v[0]) = *reinterpret_cast<const float4*>(row + ks*32 + q*8);
            *reinterpret_cast<float4*>(&v[4]) = *reinterpret_cast<const float4*>(row + ks*32 + q*8 + 4);
            short8 hi, lo;
            split8(v, hi, lo);
            tab[(mt*4 + ks)*64 + lane]     = __builtin_bit_cast(uint4, hi);
            tab[(mt*4 + 2 + ks)*64 + lane] = __builtin_bit_cast(uint4, lo);
        }
        if (l == 1) {
            float p = 0.f;
            #pragma unroll
            for (int i = 0; i < 16; ++i) p += W4l[(size_t)(w*16 + i)*64 + lane];
            csl[w][lane] = p;
            __syncthreads();
            if (t < 64) w41cs[t] = (csl[0][t] + csl[1][t]) + (csl[2][t] + csl[3][t]);
            __syncthreads();   // protect csl reuse
            float p2 = 0.f;
            #pragma unroll
            for (int i = 0; i < 16; ++i) p2 += W3l1[(size_t)(w*16 + i)*64 + lane];
            csl[w][lane] = p2;
            __syncthreads();
            if (t < 64) w3cs[t] = (csl[0][t] + csl[1][t]) + (csl[2][t] + csl[3][t]);
        }
        return;
    }

    #pragma unroll
    for (int jj = 0; jj < 4; ++jj) {
        const int fidx = jj*1024 + t*4;
        float4 v5 = *reinterpret_cast<const float4*>(W5l + fidx);
        float4 v6 = *reinterpret_cast<const float4*>(W6l + fidx);
        const int row = fidx >> 6, col = fidx & 63;
        w5s[row*65+col+0] = v5.x; w5s[row*65+col+1] = v5.y;
        w5s[row*65+col+2] = v5.z; w5s[row*65+col+3] = v5.w;
        w6s[row*65+col+0] = v6.x; w6s[row*65+col+1] = v6.y;
        w6s[row*65+col+2] = v6.z; w6s[row*65+col+3] = v6.w;
    }
    float pcs = 0.f;
    #pragma unroll
    for (int i = 0; i < 16; ++i) pcs += W3l[(size_t)(w*16 + i)*64 + lane];
    csl[w][lane] = pcs;
    __syncthreads();
    if (t < 64) cst[t] = (csl[0][t] + csl[1][t]) + (csl[2][t] + csl[3][t]);
    __syncthreads();

    const int r = blockIdx.x * 4 + w;                 // b*256 + i
    float xr[64];
    #pragma unroll
    for (int k = 0; k < 16; ++k) {
        float4 v = *reinterpret_cast<const float4*>(Xsrc + (size_t)r*64 + k*4);
        xr[k*4+0] = v.x; xr[k*4+1] = v.y; xr[k*4+2] = v.z; xr[k*4+3] = v.w;
    }
    float aj = 0.f, ar = 0.f;
    #pragma unroll
    for (int k = 0; k < 64; ++k) {
        aj += xr[k] * w5s[lane*65 + k];
        ar += xr[k] * w6s[lane*65 + k];
    }
    // Xj in fragment-native layout: [b][tile=j>>4][mt][q*16+m][ri]
    const int b = r >> 8, j = r & 255;
    const int wj = j >> 6, jt = (j >> 4) & 3, m = j & 15;
    const int mt = lane >> 4, q = (lane >> 2) & 3, ri = lane & 3;
    Xjf[(size_t)b*16384 + (size_t)(((wj*4 + jt)*4 + mt)*64 + (q*16 + m))*4 + ri] = aj;
    Xres_ws[(size_t)r*64 + lane] = ar;
    float sv = xr[lane] * cst[lane];
    #pragma unroll
    for (int d = 1; d < 64; d <<= 1) sv += __shfl_xor(sv, d, 64);
    if (lane == 0) s_ws[r] = sv;
}

// ---- layer 0: 8-wave block per (b,i); wave w owns j-tiles 2w, 2w+1.
//      In-place bf16 plane + t1 (L2-warm writes). Fused layer-1 prep tail.
//      R8-verbatim (best measured). ----
__global__ __launch_bounds__(512, 4)
void layer0_kernel(void* Ebuf,
                   const float* __restrict__ s_ws,
                   const float* __restrict__ Xjf,
                   const float* __restrict__ Xres_ws,
                   const float* __restrict__ Xold,
                   float* __restrict__ Xnext,
                   const uint4* __restrict__ w4tab,
                   const float* __restrict__ w41cs,
                   const float* __restrict__ eg,
                   const float* __restrict__ eb,
                   const float* __restrict__ ng,
                   const float* __restrict__ nb,
                   const float* __restrict__ W5l1,
                   const float* __restrict__ W6l1,
                   const float* __restrict__ w3cs,
                   float* __restrict__ s_ws2,
                   float* __restrict__ Xjf2,
                   float* __restrict__ Xres2)
{
    __shared__ uint4 w4s[1024];        // 16 KB: W4 hi/lo fragment table
    __shared__ float att[NB];
    __shared__ float agg_lds[8][64];
    __shared__ float w5s[64*65];       // W5[1] for fused prep tail
    __shared__ float w6s[64*65];       // W6[1]
    __shared__ float xrow[64];

    const int bi  = blockIdx.x;
    const int b   = bi >> 8;
    const int tid = threadIdx.x;
    const int w   = tid >> 6;          // 0..7
    const int lane = tid & 63;
    const int m = lane & 15;
    const int q = lane >> 4;

    char* ebase = (char*)Ebuf + (size_t)bi * 65536;

    // issue this wave's E loads first (8 KB contiguous region per wave)
    float4 rawf[2][4];
    #pragma unroll
    for (int jt2 = 0; jt2 < 2; ++jt2) {
        const float* er = (const float*)ebase + (size_t)((w*2 + jt2)*16 + m) * 64;
        rawf[jt2][0] = *reinterpret_cast<const float4*>(er + q*8);
        rawf[jt2][1] = *reinterpret_cast<const float4*>(er + q*8 + 4);
        rawf[jt2][2] = *reinterpret_cast<const float4*>(er + 32 + q*8);
        rawf[jt2][3] = *reinterpret_cast<const float4*>(er + 32 + q*8 + 4);
    }

    // stage W4 fragment table (overlaps with E-load latency)
    w4s[tid]       = w4tab[tid];
    w4s[tid + 512] = w4tab[tid + 512];

    short8 bh[2][2], bl[2][2];
    #pragma unroll
    for (int jt2 = 0; jt2 < 2; ++jt2) {
        float v0[8], v1[8];
        *reinterpret_cast<float4*>(&v0[0]) = rawf[jt2][0];
        *reinterpret_cast<float4*>(&v0[4]) = rawf[jt2][1];
        *reinterpret_cast<float4*>(&v1[0]) = rawf[jt2][2];
        *reinterpret_cast<float4*>(&v1[4]) = rawf[jt2][3];
        split8(v0, bh[jt2][0], bl[jt2][0]);
        split8(v1, bh[jt2][1], bl[jt2][1]);
    }
    __syncthreads();   // w4s ready

    f4 acc[4][2] = {};
    #pragma unroll
    for (int mt = 0; mt < 4; ++mt) {
        const short8 aH0 = __builtin_bit_cast(short8, w4s[(mt*4 + 0)*64 + lane]);
        const short8 aH1 = __builtin_bit_cast(short8, w4s[(mt*4 + 1)*64 + lane]);
        const short8 aL0 = __builtin_bit_cast(short8, w4s[(mt*4 + 2)*64 + lane]);
        const short8 aL1 = __builtin_bit_cast(short8, w4s[(mt*4 + 3)*64 + lane]);
        #pragma unroll
        for (int jt2 = 0; jt2 < 2; ++jt2) {
            acc[mt][jt2] = __builtin_amdgcn_mfma_f32_16x16x32_bf16(aH0, bh[jt2][0], acc[mt][jt2], 0, 0, 0);
            acc[mt][jt2] = __builtin_amdgcn_mfma_f32_16x16x32_bf16(aL0, bh[jt2][0], acc[mt][jt2], 0, 0, 0);
            acc[mt][jt2] = __builtin_amdgcn_mfma_f32_16x16x32_bf16(aH0, bl[jt2][0], acc[mt][jt2], 0, 0, 0);
            acc[mt][jt2] = __builtin_amdgcn_mfma_f32_16x16x32_bf16(aH1, bh[jt2][1], acc[mt][jt2], 0, 0, 0);
            acc[mt][jt2] = __builtin_amdgcn_mfma_f32_16x16x32_bf16(aL1, bh[jt2][1], acc[mt][jt2], 0, 0, 0);
            acc[mt][jt2] = __builtin_amdgcn_mfma_f32_16x16x32_bf16(aH1, bl[jt2][1], acc[mt][jt2], 0, 0, 0);
        }
    }

    // colsum(E_hat) -> att logits (partial, per-tile)
    #pragma unroll
    for (int jt2 = 0; jt2 < 2; ++jt2) {
        float t = 0.f;
        #pragma unroll
        for (int mt = 0; mt < 4; ++mt)
            #pragma unroll
            for (int r = 0; r < 4; ++r) t += acc[mt][jt2][r];
        t += __shfl_xor(t, 16, 64);
        t += __shfl_xor(t, 32, 64);
        if (lane < 16) att[(w*2 + jt2)*16 + lane] = t;
    }
    __syncthreads();

    // per-wave full softmax (redundant across waves; pure register/shuffle)
    const float si = s_ws[bi];
    const float* srow = s_ws + b*NB;
    float l0 = att[lane      ] + si + srow[lane      ];
    float l1 = att[lane +  64] + si + srow[lane +  64];
    float l2 = att[lane + 128] + si + srow[lane + 128];
    float l3 = att[lane + 192] + si + srow[lane + 192];
    float mx = fmaxf(fmaxf(l0, l1), fmaxf(l2, l3));
    #pragma unroll
    for (int d = 1; d < 64; d <<= 1) mx = fmaxf(mx, __shfl_xor(mx, d, 64));
    const float e0 = __expf(l0 - mx), e1 = __expf(l1 - mx);
    const float e2 = __expf(l2 - mx), e3 = __expf(l3 - mx);
    float sme = (e0 + e1) + (e2 + e3);
    #pragma unroll
    for (int d = 1; d < 64; d <<= 1) sme += __shfl_xor(sme, d, 64);
    // this wave's j-range [32w, 32w+32) lies in chunk cw = w>>1
    const int cw = w >> 1;
    float evw = (cw == 0) ? e0 : (cw == 1) ? e1 : (cw == 2) ? e2 : e3;
    evw *= 1.f / sme;
    const float attv0 = __shfl(evw, (w & 1)*32 + m,      64);
    const float attv1 = __shfl(evw, (w & 1)*32 + 16 + m, 64);

    #pragma unroll
    for (int mt = 0; mt < 4; ++mt)
        #pragma unroll
        for (int r = 0; r < 4; ++r) {
            acc[mt][0][r] *= attv0;
            acc[mt][1][r] *= attv1;
        }

    // agg partial: einsum over this wave's 32 j
    float p[4][4] = {};
    #pragma unroll
    for (int jt2 = 0; jt2 < 2; ++jt2)
        #pragma unroll
        for (int mt = 0; mt < 4; ++mt) {
            float4 xv = *reinterpret_cast<const float4*>(
                Xjf + (size_t)b*16384 + (size_t)(((w*2 + jt2)*4 + mt)*64 + lane)*4);
            p[mt][0] += acc[mt][jt2][0] * xv.x;
            p[mt][1] += acc[mt][jt2][1] * xv.y;
            p[mt][2] += acc[mt][jt2][2] * xv.z;
            p[mt][3] += acc[mt][jt2][3] * xv.w;
        }
    #pragma unroll
    for (int d = 1; d < 16; d <<= 1)
        #pragma unroll
        for (int mt = 0; mt < 4; ++mt)
            #pragma unroll
            for (int r = 0; r < 4; ++r) p[mt][r] += __shfl_xor(p[mt][r], d, 64);
    if (m == 0) {
        #pragma unroll
        for (int mt = 0; mt < 4; ++mt) {
            float4 st = make_float4(p[mt][0], p[mt][1], p[mt][2], p[mt][3]);
            *reinterpret_cast<float4*>(&agg_lds[w][mt*16 + q*4]) = st;
        }
    }

    // LN stats + bf16 plane store (B-frag layout) + exact t1
    {
        float mean[2], rstd[2];
        #pragma unroll
        for (int jt2 = 0; jt2 < 2; ++jt2) {
            float s = 0.f, ss = 0.f;
            #pragma unroll
            for (int mt = 0; mt < 4; ++mt)
                #pragma unroll
                for (int r = 0; r < 4; ++r) { float vv = acc[mt][jt2][r]; s += vv; ss += vv*vv; }
            s  += __shfl_xor(s, 16, 64);  s  += __shfl_xor(s, 32, 64);
            ss += __shfl_xor(ss, 16, 64); ss += __shfl_xor(ss, 32, 64);
            float mu = s * (1.f/64.f);
            mean[jt2] = mu;
            rstd[jt2] = rsqrtf(ss * (1.f/64.f) - mu*mu + 1e-5f);
        }
        float egv[4][4], ebv[4][4], wcs[4][4];
        #pragma unroll
        for (int mt = 0; mt < 4; ++mt)
            #pragma unroll
            for (int r = 0; r < 4; ++r) {
                const int c = mt*16 + q*4 + r;
                egv[mt][r] = eg[c];
                ebv[mt][r] = eb[c];
                wcs[mt][r] = w41cs[c];
            }
        float* t1g = (float*)(ebase + 32768);
        float t1p[2] = {0.f, 0.f};
        #pragma unroll
        for (int jt2 = 0; jt2 < 2; ++jt2) {
            #pragma unroll
            for (int mt = 0; mt < 4; ++mt) {
                float o[4];
                #pragma unroll
                for (int r = 0; r < 4; ++r) {
                    o[r] = (acc[mt][jt2][r] - mean[jt2]) * rstd[jt2] * egv[mt][r] + ebv[mt][r];
                    t1p[jt2] += o[r] * wcs[mt][r];
                }
                uint2 u2;
                u2.x = ((unsigned int)f2bfbits(o[1]) << 16) | (unsigned int)f2bfbits(o[0]);
                u2.y = ((unsigned int)f2bfbits(o[3]) << 16) | (unsigned int)f2bfbits(o[2]);
                const int qp = (2*mt + (q >> 1)) & 3;
                const size_t addr = (size_t)((((w*2 + jt2)*2 + (mt >> 1))*64 + qp*16 + m))*16 + (q & 1)*8;
                *reinterpret_cast<uint2*>(ebase + addr) = u2;
            }
        }
        #pragma unroll
        for (int jt2 = 0; jt2 < 2; ++jt2) {
            float tv = t1p[jt2];
            tv += __shfl_xor(tv, 16, 64);
            tv += __shfl_xor(tv, 32, 64);
            if (lane < 16) t1g[(w*2 + jt2)*16 + lane] = tv;
        }
    }

    // stage W5[1]/W6[1] for the fused prep tail (all 512 threads, 4 float4s)
    #pragma unroll
    for (int jj = 0; jj < 2; ++jj) {
        const int fidx = jj*2048 + tid*4;
        float4 v5 = *reinterpret_cast<const float4*>(W5l1 + fidx);
        float4 v6 = *reinterpret_cast<const float4*>(W6l1 + fidx);
        const int row = fidx >> 6, col = fidx & 63;
        w5s[row*65+col+0] = v5.x; w5s[row*65+col+1] = v5.y;
        w5s[row*65+col+2] = v5.z; w5s[row*65+col+3] = v5.w;
        w6s[row*65+col+0] = v6.x; w6s[row*65+col+1] = v6.y;
        w6s[row*65+col+2] = v6.z; w6s[row*65+col+3] = v6.w;
    }
    __syncthreads();

    if (w == 0) {
        float a = ((agg_lds[0][lane] + agg_lds[1][lane]) + (agg_lds[2][lane] + agg_lds[3][lane]))
                + ((agg_lds[4][lane] + agg_lds[5][lane]) + (agg_lds[6][lane] + agg_lds[7][lane]));
        float v = fmaxf(a + Xres_ws[(size_t)bi*64 + lane], 0.f);
        float s = v, ss = v*v;
        #pragma unroll
        for (int d = 1; d < 64; d <<= 1) { s += __shfl_xor(s, d, 64); ss += __shfl_xor(ss, d, 64); }
        float mu  = s * (1.f/64.f);
        float var = ss * (1.f/64.f) - mu*mu;
        const float xa = (v - mu) * rsqrtf(var + 1e-5f) * ng[lane] + nb[lane]
                       + Xold[(size_t)bi*64 + lane];
        Xnext[(size_t)bi*64 + lane] = xa;

        // ---- fused layer-1 prep for this row (was prep_kernel<false>) ----
        xrow[lane] = xa;                      // wave-local LDS broadcast buffer
        float aj = 0.f, ar = 0.f;
        #pragma unroll
        for (int k = 0; k < 64; ++k) {
            const float xk = xrow[k];         // broadcast read
            aj += xk * w5s[lane*65 + k];
            ar += xk * w6s[lane*65 + k];
        }
        const int j2 = bi & 255;
        const int wj = j2 >> 6, jt3 = (j2 >> 4) & 3, mm = j2 & 15;
        const int mt3 = lane >> 4, qq = (lane >> 2) & 3, ri = lane & 3;
        Xjf2[(size_t)b*16384 + (size_t)(((wj*4 + jt3)*4 + mt3)*64 + (qq*16 + mm))*4 + ri] = aj;
        Xres2[(size_t)bi*64 + lane] = ar;
        float sv = xa * w3cs[lane];
        #pragma unroll
        for (int d = 1; d < 64; d <<= 1) sv += __shfl_xor(sv, d, 64);
        if (lane == 0) s_ws2[bi] = sv;
    }
}

// ---- layer 1 + head: TWO waves per (b,i) — wave pair splits the 4 j-chunks
//      2+2, combining partials via 1 KB LDS + one barrier. Grid 1024 ->
//      4096 waves = 16 waves/CU (2x the grid-limited 8 of the 1-wave form).
//      Head weights LDS-staged once per block (amortized over 2 bi). ----
__global__ __launch_bounds__(256)
void layer1_kernel(const void* __restrict__ Ebuf,
                   const float* __restrict__ s_ws,
                   const float* __restrict__ Xjf,
                   const float* __restrict__ Xres_ws,
                   const float* __restrict__ Xold,
                   const uint4* __restrict__ w4tab,
                   const float* __restrict__ ng,
                   const float* __restrict__ nb,
                   const float* __restrict__ hw1,
                   const float* __restrict__ hb1,
                   const float* __restrict__ hw2,
                   const float* __restrict__ hb2,
                   float* __restrict__ outp)
{
    __shared__ float w1s[64*65];
    __shared__ float w2s[10*65];
    __shared__ float pp[4][64];

    const int tid = threadIdx.x;
    const int w = tid >> 6, lane = tid & 63;
    const int ws = w & 1;                  // sub-wave within the pair
    const int m = lane & 15, q = lane >> 4;

    // stage head weights (once per block; amortized over 2 bi)
    #pragma unroll
    for (int jj = 0; jj < 4; ++jj) {
        const int fidx = jj*1024 + tid*4;
        float4 v = *reinterpret_cast<const float4*>(hw1 + fidx);
        const int row = fidx >> 6, col = fidx & 63;
        w1s[row*65+col+0] = v.x; w1s[row*65+col+1] = v.y;
        w1s[row*65+col+2] = v.z; w1s[row*65+col+3] = v.w;
    }
    if (tid < 160) {
        const int fidx = tid*4;
        float4 v = *reinterpret_cast<const float4*>(hw2 + fidx);
        const int row = fidx >> 6, col = fidx & 63;
        w2s[row*65+col+0] = v.x; w2s[row*65+col+1] = v.y;
        w2s[row*65+col+2] = v.z; w2s[row*65+col+3] = v.w;
    }
    __syncthreads();

    const int bi = blockIdx.x * 2 + (w >> 1);   // b*256 + i
    const int b  = bi >> 8;
    const char* ebase = (const char*)Ebuf + (size_t)bi * 65536;
    const float* t1g = (const float*)(ebase + 32768);

    // ---- softmax from precomputed t1 (per-wave, pure wave ops) ----
    const float si = s_ws[bi];
    const float* srow = s_ws + b*NB;
    float l0 = t1g[lane      ] + si + srow[lane      ];
    float l1 = t1g[lane +  64] + si + srow[lane +  64];
    float l2 = t1g[lane + 128] + si + srow[lane + 128];
    float l3 = t1g[lane + 192] + si + srow[lane + 192];
    float mx = fmaxf(fmaxf(l0, l1), fmaxf(l2, l3));
    #pragma unroll
    for (int d = 1; d < 64; d <<= 1) mx = fmaxf(mx, __shfl_xor(mx, d, 64));
    l0 = __expf(l0 - mx); l1 = __expf(l1 - mx);
    l2 = __expf(l2 - mx); l3 = __expf(l3 - mx);
    float sme = (l0 + l1) + (l2 + l3);
    #pragma unroll
    for (int d = 1; d < 64; d <<= 1) sme += __shfl_xor(sme, d, 64);
    const float inv = 1.f / sme;
    // this wave's two chunks: cA = 2*ws, cB = 2*ws+1 (named scalars, no
    // runtime array indexing -> no scratch)
    const float lA = (ws ? l2 : l0) * inv;
    const float lB = (ws ? l3 : l1) * inv;
    const int cA = 2*ws;

    // A fragments (hi-only), L2-hot
    short8 aH[4][2];
    #pragma unroll
    for (int mt = 0; mt < 4; ++mt) {
        aH[mt][0] = __builtin_bit_cast(short8, w4tab[(mt*4 + 0)*64 + lane]);
        aH[mt][1] = __builtin_bit_cast(short8, w4tab[(mt*4 + 1)*64 + lane]);
    }

    // ---- this wave's two chunks (A then B; B's loads issued during A) ----
    float p[4][4] = {};
    uint4 rbA[4][2], rbB[4][2];
    #pragma unroll
    for (int jt = 0; jt < 4; ++jt)
        #pragma unroll
        for (int ks = 0; ks < 2; ++ks)
            rbA[jt][ks] = *reinterpret_cast<const uint4*>(
                ebase + (size_t)(((cA*4 + jt)*2 + ks)*64 + lane) * 16);
    #pragma unroll
    for (int jt = 0; jt < 4; ++jt)
        #pragma unroll
        for (int ks = 0; ks < 2; ++ks)
            rbB[jt][ks] = *reinterpret_cast<const uint4*>(
                ebase + (size_t)((((cA+1)*4 + jt)*2 + ks)*64 + lane) * 16);

    #pragma unroll
    for (int cc = 0; cc < 2; ++cc) {
        const int c = cA + cc;
        const float lv = cc ? lB : lA;
        #pragma unroll
        for (int jt = 0; jt < 4; ++jt) {
            short8 b0 = __builtin_bit_cast(short8, cc ? rbB[jt][0] : rbA[jt][0]);
            short8 b1 = __builtin_bit_cast(short8, cc ? rbB[jt][1] : rbA[jt][1]);
            f4 a0 = {}, a1 = {}, a2 = {}, a3 = {};
            a0 = __builtin_amdgcn_mfma_f32_16x16x32_bf16(aH[0][0], b0, a0, 0, 0, 0);
            a0 = __builtin_amdgcn_mfma_f32_16x16x32_bf16(aH[0][1], b1, a0, 0, 0, 0);
            a1 = __builtin_amdgcn_mfma_f32_16x16x32_bf16(aH[1][0], b0, a1, 0, 0, 0);
            a1 = __builtin_amdgcn_mfma_f32_16x16x32_bf16(aH[1][1], b1, a1, 0, 0, 0);
            a2 = __builtin_amdgcn_mfma_f32_16x16x32_bf16(aH[2][0], b0, a2, 0, 0, 0);
            a2 = __builtin_amdgcn_mfma_f32_16x16x32_bf16(aH[2][1], b1, a2, 0, 0, 0);
            a3 = __builtin_amdgcn_mfma_f32_16x16x32_bf16(aH[3][0], b0, a3, 0, 0, 0);
            a3 = __builtin_amdgcn_mfma_f32_16x16x32_bf16(aH[3][1], b1, a3, 0, 0, 0);
            const float av = __shfl(lv, jt*16 + m, 64);
            const float* xb = Xjf + (size_t)b*16384 + (size_t)(((c*4 + jt)*4)*64 + lane)*4;
            float4 x0 = *reinterpret_cast<const float4*>(xb);
            float4 x1 = *reinterpret_cast<const float4*>(xb + 256);
            float4 x2 = *reinterpret_cast<const float4*>(xb + 512);
            float4 x3 = *reinterpret_cast<const float4*>(xb + 768);
            p[0][0] += a0[0]*av*x0.x; p[0][1] += a0[1]*av*x0.y;
            p[0][2] += a0[2]*av*x0.z; p[0][3] += a0[3]*av*x0.w;
            p[1][0] += a1[0]*av*x1.x; p[1][1] += a1[1]*av*x1.y;
            p[1][2] += a1[2]*av*x1.z; p[1][3] += a1[3]*av*x1.w;
            p[2][0] += a2[0]*av*x2.x; p[2][1] += a2[1]*av*x2.y;
            p[2][2] += a2[2]*av*x2.z; p[2][3] += a2[3]*av*x2.w;
            p[3][0] += a3[0]*av*x3.x; p[3][1] += a3[1]*av*x3.y;
            p[3][2] += a3[2]*av*x3.z; p[3][3] += a3[3]*av*x3.w;
        }
    }

    // butterfly-reduce over the 16 m-lanes: all lanes end with partial agg
    // for h = mt*16 + q*4 + r
    #pragma unroll
    for (int d = 1; d < 16; d <<= 1)
        #pragma unroll
        for (int mt = 0; mt < 4; ++mt)
            #pragma unroll
            for (int r = 0; r < 4; ++r) p[mt][r] += __shfl_xor(p[mt][r], d, 64);

    // pair combine via LDS (1 KB) + one barrier
    if (m == 0) {
        #pragma unroll
        for (int mt = 0; mt < 4; ++mt)
            *reinterpret_cast<float4*>(&pp[w][mt*16 + q*4]) =
                make_float4(p[mt][0], p[mt][1], p[mt][2], p[mt][3]);
    }
    __syncthreads();
    if (ws == 1) return;

    #pragma unroll
    for (int mt = 0; mt < 4; ++mt) {
        float4 t0 = *reinterpret_cast<const float4*>(&pp[w][mt*16 + q*4]);
        float4 t1 = *reinterpret_cast<const float4*>(&pp[w+1][mt*16 + q*4]);
        p[mt][0] = t0.x + t1.x;
        p[mt][1] = t0.y + t1.y;
        p[mt][2] = t0.z + t1.z;
        p[mt][3] = t0.w + t1.w;
    }

    // per-wave X-update: v = relu(agg + Xres), LN over h, + Xold
    float4 xres[4], xold[4], ngv[4], nbv[4];
    #pragma unroll
    for (int mt = 0; mt < 4; ++mt) {
        const int hb = mt*16 + q*4;
        xres[mt] = *reinterpret_cast<const float4*>(Xres_ws + (size_t)bi*64 + hb);
        xold[mt] = *reinterpret_cast<const float4*>(Xold    + (size_t)bi*64 + hb);
        ngv[mt]  = *reinterpret_cast<const float4*>(ng + hb);
        nbv[mt]  = *reinterpret_cast<const float4*>(nb + hb);
    }
    float v[4][4];
    float s = 0.f, ss = 0.f;
    #pragma unroll
    for (int mt = 0; mt < 4; ++mt) {
        v[mt][0] = fmaxf(p[mt][0] + xres[mt].x, 0.f);
        v[mt][1] = fmaxf(p[mt][1] + xres[mt].y, 0.f);
        v[mt][2] = fmaxf(p[mt][2] + xres[mt].z, 0.f);
        v[mt][3] = fmaxf(p[mt][3] + xres[mt].w, 0.f);
        #pragma unroll
        for (int r = 0; r < 4; ++r) { s += v[mt][r]; ss += v[mt][r]*v[mt][r]; }
    }
    s  += __shfl_xor(s, 16, 64);  s  += __shfl_xor(s, 32, 64);
    ss += __shfl_xor(ss, 16, 64); ss += __shfl_xor(ss, 32, 64);
    const float mu   = s * (1.f/64.f);
    const float rstd = rsqrtf(ss * (1.f/64.f) - mu*mu + 1e-5f);
    float xf[4][4];
    #pragma unroll
    for (int mt = 0; mt < 4; ++mt) {
        xf[mt][0] = (v[mt][0] - mu) * rstd * ngv[mt].x + nbv[mt].x + xold[mt].x;
        xf[mt][1] = (v[mt][1] - mu) * rstd * ngv[mt].y + nbv[mt].y + xold[mt].y;
        xf[mt][2] = (v[mt][2] - mu) * rstd * ngv[mt].z + nbv[mt].z + xold[mt].z;
        xf[mt][3] = (v[mt][3] - mu) * rstd * ngv[mt].w + nbv[mt].w + xold[mt].w;
    }

    // ---- fused head (per-wave, X broadcast via shuffles) ----
    float h1 = hb1[lane];
    #pragma unroll
    for (int mt = 0; mt < 4; ++mt)
        #pragma unroll
        for (int q2 = 0; q2 < 4; ++q2)
            #pragma unroll
            for (int r = 0; r < 4; ++r) {
                const float xv = __shfl(xf[mt][r], q2*16, 64);
                h1 += xv * w1s[lane*65 + mt*16 + q2*4 + r];
            }
    h1 = fmaxf(h1, 0.f);
    float pa[10];
    #pragma unroll
    for (int a = 0; a < 10; ++a) pa[a] = h1 * w2s[a*65 + lane];
    #pragma unroll
    for (int d = 1; d < 64; d <<= 1)
        #pragma unroll
        for (int a = 0; a < 10; ++a) pa[a] += __shfl_xor(pa[a], d, 64);
    if (lane == 0) {
        #pragma unroll
        for (int a = 0; a < 10; ++a) outp[(size_t)bi*10 + a] = pa[a] + hb2[a];
    }
}

extern "C" void kernel_launch(void* const* d_in, const int* in_sizes, int n_in,
                              void* d_out, int out_size, void* d_ws, size_t ws_size,
                              hipStream_t stream) {
    const float* X   = (const float*)d_in[0];
    void*        E   = (void*)d_in[1];           // f32 in; bf16 plane + t1 written in place
    const float* W3  = (const float*)d_in[2];
    const float* W4  = (const float*)d_in[3];
    const float* W5  = (const float*)d_in[4];
    const float* W6  = (const float*)d_in[5];
    const float* ng  = (const float*)d_in[6];
    const float* nbp = (const float*)d_in[7];
    const float* eg  = (const float*)d_in[8];
    const float* ebp = (const float*)d_in[9];
    const float* hw1 = (const float*)d_in[10];
    const float* hb1 = (const float*)d_in[11];
    const float* hw2 = (const float*)d_in[12];
    const float* hb2 = (const float*)d_in[13];
    float* outp = (float*)d_out;

    float* wsf   = (float*)d_ws;
    float* s_ws  = wsf;                    // 2048
    float* Xjf   = wsf + 2048;             // 131072
    float* Xres  = wsf + 133120;           // 131072
    float* Xa    = wsf + 264192;           // 131072
    float* w41cs = wsf + 395264;           // 64
    float* w3cs  = wsf + 395328;           // 64
    uint4* w4tab = (uint4*)(wsf + 395392); // 2048 uint4 (32 KB) -> ends 403584
    float* s2    = wsf + 403584;           // 2048
    float* Xjf2  = wsf + 405632;           // 131072
    float* Xres2 = wsf + 536704;           // 131072

    // prep (layer-0 rows; blocks 512/513 build W4 tables + colsums)
    prep_kernel<<<514, 256, 0, stream>>>(X, W3, W5, W6, W4, w4tab, w41cs,
        W3 + 4096, w3cs, s_ws, Xjf, Xres);
    // layer 0 with fused layer-1 prep tail (R8-verbatim, best measured)
    layer0_kernel<<<2048, 512, 0, stream>>>(E, s_ws, Xjf, Xres,
        X, Xa, w4tab, w41cs, eg, ebp, ng, nbp,
        W5 + 4096, W6 + 4096, w3cs, s2, Xjf2, Xres2);
    // layer 1 + fused head (2-wave-per-bi split, grid 1024 -> 16 waves/CU)
    layer1_kernel<<<1024, 256, 0, stream>>>(E, s2, Xjf2, Xres2,
        Xa, w4tab + 1024, ng + 64, nbp + 64, hw1, hb1, hw2, hb2, outp);
}

// Round 11
// 273.323 us; speedup vs baseline: 1.0356x; 1.0356x over previous
//
#include <hip/hip_runtime.h>
#include <hip/hip_bf16.h>

#define NB 256   // nodes
#define HH 64    // hidden

using short8 = __attribute__((ext_vector_type(8))) short;
using f4     = __attribute__((ext_vector_type(4))) float;

static __device__ __forceinline__ unsigned short f2bfbits(float f) {
    __hip_bfloat16 h = __float2bfloat16(f);
    return __builtin_bit_cast(unsigned short, h);
}
static __device__ __forceinline__ float bfbits2f(unsigned short u) {
    unsigned int x = (unsigned int)u << 16;
    return __builtin_bit_cast(float, x);
}

// split 8 f32 -> hi (RNE bf16) + lo (RNE residual bf16); v ~= hi + lo (~2^-17)
static __device__ __forceinline__ void split8(const float* v, short8& hi, short8& lo) {
    unsigned int hd[4], ld[4];
    #pragma unroll
    for (int j = 0; j < 4; ++j) {
        unsigned short h0 = f2bfbits(v[2*j]);
        unsigned short h1 = f2bfbits(v[2*j+1]);
        hd[j] = ((unsigned int)h1 << 16) | (unsigned int)h0;
        float r0 = v[2*j]   - bfbits2f(h0);
        float r1 = v[2*j+1] - bfbits2f(h1);
        ld[j] = ((unsigned int)f2bfbits(r1) << 16) | (unsigned int)f2bfbits(r0);
    }
    uint4 h4; h4.x = hd[0]; h4.y = hd[1]; h4.z = hd[2]; h4.w = hd[3];
    uint4 l4; l4.x = ld[0]; l4.y = ld[1]; l4.z = ld[2]; l4.w = ld[3];
    hi = __builtin_bit_cast(short8, h4);
    lo = __builtin_bit_cast(short8, l4);
}

// ---- prep (layer 0 only): per-row s, Xj, Xres from X; BUILD blocks also
//      make the W4 fragment tables, colsum(W4[1]) and colsum(W3[1]). ----
__global__ __launch_bounds__(256)
void prep_kernel(const float* __restrict__ Xsrc,
                 const float* __restrict__ W3l,
                 const float* __restrict__ W5l,
                 const float* __restrict__ W6l,
                 const float* __restrict__ W4all,
                 uint4* __restrict__ w4tab,
                 float* __restrict__ w41cs,
                 const float* __restrict__ W3l1,
                 float* __restrict__ w3cs,
                 float* __restrict__ s_ws,
                 float* __restrict__ Xjf,
                 float* __restrict__ Xres_ws)
{
    __shared__ float w5s[64*65];
    __shared__ float w6s[64*65];
    __shared__ float csl[4][64];
    __shared__ float cst[64];
    const int t = threadIdx.x;
    const int w = t >> 6, lane = t & 63;

    if (blockIdx.x >= 512) {
        const int l = blockIdx.x - 512;
        const float* W4l = W4all + (size_t)l * 4096;
        uint4* tab = w4tab + (size_t)l * 1024;
        const int mt = w, m = lane & 15, q = lane >> 4;
        const float* row = W4l + (size_t)(mt*16 + m) * 64;
        #pragma unroll
        for (int ks = 0; ks < 2; ++ks) {
            float v[8];
            *reinterpret_cast<float4*>(&v[0]) = *reinterpret_cast<const float4*>(row + ks*32 + q*8);
            *reinterpret_cast<float4*>(&v[4]) = *reinterpret_cast<const float4*>(row + ks*32 + q*8 + 4);
            short8 hi, lo;
            split8(v, hi, lo);
            tab[(mt*4 + ks)*64 + lane]     = __builtin_bit_cast(uint4, hi);
            tab[(mt*4 + 2 + ks)*64 + lane] = __builtin_bit_cast(uint4, lo);
        }
        if (l == 1) {
            float p = 0.f;
            #pragma unroll
            for (int i = 0; i < 16; ++i) p += W4l[(size_t)(w*16 + i)*64 + lane];
            csl[w][lane] = p;
            __syncthreads();
            if (t < 64) w41cs[t] = (csl[0][t] + csl[1][t]) + (csl[2][t] + csl[3][t]);
            __syncthreads();   // protect csl reuse
            float p2 = 0.f;
            #pragma unroll
            for (int i = 0; i < 16; ++i) p2 += W3l1[(size_t)(w*16 + i)*64 + lane];
            csl[w][lane] = p2;
            __syncthreads();
            if (t < 64) w3cs[t] = (csl[0][t] + csl[1][t]) + (csl[2][t] + csl[3][t]);
        }
        return;
    }

    #pragma unroll
    for (int jj = 0; jj < 4; ++jj) {
        const int fidx = jj*1024 + t*4;
        float4 v5 = *reinterpret_cast<const float4*>(W5l + fidx);
        float4 v6 = *reinterpret_cast<const float4*>(W6l + fidx);
        const int row = fidx >> 6, col = fidx & 63;
        w5s[row*65+col+0] = v5.x; w5s[row*65+col+1] = v5.y;
        w5s[row*65+col+2] = v5.z; w5s[row*65+col+3] = v5.w;
        w6s[row*65+col+0] = v6.x; w6s[row*65+col+1] = v6.y;
        w6s[row*65+col+2] = v6.z; w6s[row*65+col+3] = v6.w;
    }
    float pcs = 0.f;
    #pragma unroll
    for (int i = 0; i < 16; ++i) pcs += W3l[(size_t)(w*16 + i)*64 + lane];
    csl[w][lane] = pcs;
    __syncthreads();
    if (t < 64) cst[t] = (csl[0][t] + csl[1][t]) + (csl[2][t] + csl[3][t]);
    __syncthreads();

    const int r = blockIdx.x * 4 + w;                 // b*256 + i
    float xr[64];
    #pragma unroll
    for (int k = 0; k < 16; ++k) {
        float4 v = *reinterpret_cast<const float4*>(Xsrc + (size_t)r*64 + k*4);
        xr[k*4+0] = v.x; xr[k*4+1] = v.y; xr[k*4+2] = v.z; xr[k*4+3] = v.w;
    }
    float aj = 0.f, ar = 0.f;
    #pragma unroll
    for (int k = 0; k < 64; ++k) {
        aj += xr[k] * w5s[lane*65 + k];
        ar += xr[k] * w6s[lane*65 + k];
    }
    // Xj in fragment-native layout: [b][tile=j>>4][mt][q*16+m][ri]
    const int b = r >> 8, j = r & 255;
    const int wj = j >> 6, jt = (j >> 4) & 3, m = j & 15;
    const int mt = lane >> 4, q = (lane >> 2) & 3, ri = lane & 3;
    Xjf[(size_t)b*16384 + (size_t)(((wj*4 + jt)*4 + mt)*64 + (q*16 + m))*4 + ri] = aj;
    Xres_ws[(size_t)r*64 + lane] = ar;
    float sv = xr[lane] * cst[lane];
    #pragma unroll
    for (int d = 1; d < 64; d <<= 1) sv += __shfl_xor(sv, d, 64);
    if (lane == 0) s_ws[r] = sv;
}

// ---- layer 0: 8-wave block per (b,i); wave w owns j-tiles 2w, 2w+1.
//      In-place bf16 plane + t1 (L2-warm writes). FUSED TAIL: w0 computes
//      layer1's prep (s2/Xjf2/Xres2) from the Xa row it already holds. ----
__global__ __launch_bounds__(512, 4)
void layer0_kernel(void* Ebuf,
                   const float* __restrict__ s_ws,
                   const float* __restrict__ Xjf,
                   const float* __restrict__ Xres_ws,
                   const float* __restrict__ Xold,
                   float* __restrict__ Xnext,
                   const uint4* __restrict__ w4tab,
                   const float* __restrict__ w41cs,
                   const float* __restrict__ eg,
                   const float* __restrict__ eb,
                   const float* __restrict__ ng,
                   const float* __restrict__ nb,
                   const float* __restrict__ W5l1,
                   const float* __restrict__ W6l1,
                   const float* __restrict__ w3cs,
                   float* __restrict__ s_ws2,
                   float* __restrict__ Xjf2,
                   float* __restrict__ Xres2)
{
    __shared__ uint4 w4s[1024];        // 16 KB: W4 hi/lo fragment table
    __shared__ float att[NB];
    __shared__ float agg_lds[8][64];
    __shared__ float w5s[64*65];       // W5[1] for fused prep tail
    __shared__ float w6s[64*65];       // W6[1]
    __shared__ float xrow[64];

    const int bi  = blockIdx.x;
    const int b   = bi >> 8;
    const int tid = threadIdx.x;
    const int w   = tid >> 6;          // 0..7
    const int lane = tid & 63;
    const int m = lane & 15;
    const int q = lane >> 4;

    char* ebase = (char*)Ebuf + (size_t)bi * 65536;

    // issue this wave's E loads first (8 KB contiguous region per wave)
    float4 rawf[2][4];
    #pragma unroll
    for (int jt2 = 0; jt2 < 2; ++jt2) {
        const float* er = (const float*)ebase + (size_t)((w*2 + jt2)*16 + m) * 64;
        rawf[jt2][0] = *reinterpret_cast<const float4*>(er + q*8);
        rawf[jt2][1] = *reinterpret_cast<const float4*>(er + q*8 + 4);
        rawf[jt2][2] = *reinterpret_cast<const float4*>(er + 32 + q*8);
        rawf[jt2][3] = *reinterpret_cast<const float4*>(er + 32 + q*8 + 4);
    }

    // stage W4 fragment table (overlaps with E-load latency)
    w4s[tid]       = w4tab[tid];
    w4s[tid + 512] = w4tab[tid + 512];

    short8 bh[2][2], bl[2][2];
    #pragma unroll
    for (int jt2 = 0; jt2 < 2; ++jt2) {
        float v0[8], v1[8];
        *reinterpret_cast<float4*>(&v0[0]) = rawf[jt2][0];
        *reinterpret_cast<float4*>(&v0[4]) = rawf[jt2][1];
        *reinterpret_cast<float4*>(&v1[0]) = rawf[jt2][2];
        *reinterpret_cast<float4*>(&v1[4]) = rawf[jt2][3];
        split8(v0, bh[jt2][0], bl[jt2][0]);
        split8(v1, bh[jt2][1], bl[jt2][1]);
    }
    __syncthreads();   // w4s ready

    f4 acc[4][2] = {};
    #pragma unroll
    for (int mt = 0; mt < 4; ++mt) {
        const short8 aH0 = __builtin_bit_cast(short8, w4s[(mt*4 + 0)*64 + lane]);
        const short8 aH1 = __builtin_bit_cast(short8, w4s[(mt*4 + 1)*64 + lane]);
        const short8 aL0 = __builtin_bit_cast(short8, w4s[(mt*4 + 2)*64 + lane]);
        const short8 aL1 = __builtin_bit_cast(short8, w4s[(mt*4 + 3)*64 + lane]);
        #pragma unroll
        for (int jt2 = 0; jt2 < 2; ++jt2) {
            acc[mt][jt2] = __builtin_amdgcn_mfma_f32_16x16x32_bf16(aH0, bh[jt2][0], acc[mt][jt2], 0, 0, 0);
            acc[mt][jt2] = __builtin_amdgcn_mfma_f32_16x16x32_bf16(aL0, bh[jt2][0], acc[mt][jt2], 0, 0, 0);
            acc[mt][jt2] = __builtin_amdgcn_mfma_f32_16x16x32_bf16(aH0, bl[jt2][0], acc[mt][jt2], 0, 0, 0);
            acc[mt][jt2] = __builtin_amdgcn_mfma_f32_16x16x32_bf16(aH1, bh[jt2][1], acc[mt][jt2], 0, 0, 0);
            acc[mt][jt2] = __builtin_amdgcn_mfma_f32_16x16x32_bf16(aL1, bh[jt2][1], acc[mt][jt2], 0, 0, 0);
            acc[mt][jt2] = __builtin_amdgcn_mfma_f32_16x16x32_bf16(aH1, bl[jt2][1], acc[mt][jt2], 0, 0, 0);
        }
    }

    // colsum(E_hat) -> att logits (partial, per-tile)
    #pragma unroll
    for (int jt2 = 0; jt2 < 2; ++jt2) {
        float t = 0.f;
        #pragma unroll
        for (int mt = 0; mt < 4; ++mt)
            #pragma unroll
            for (int r = 0; r < 4; ++r) t += acc[mt][jt2][r];
        t += __shfl_xor(t, 16, 64);
        t += __shfl_xor(t, 32, 64);
        if (lane < 16) att[(w*2 + jt2)*16 + lane] = t;
    }
    __syncthreads();

    // per-wave full softmax (redundant across waves; pure register/shuffle)
    const float si = s_ws[bi];
    const float* srow = s_ws + b*NB;
    float l0 = att[lane      ] + si + srow[lane      ];
    float l1 = att[lane +  64] + si + srow[lane +  64];
    float l2 = att[lane + 128] + si + srow[lane + 128];
    float l3 = att[lane + 192] + si + srow[lane + 192];
    float mx = fmaxf(fmaxf(l0, l1), fmaxf(l2, l3));
    #pragma unroll
    for (int d = 1; d < 64; d <<= 1) mx = fmaxf(mx, __shfl_xor(mx, d, 64));
    const float e0 = __expf(l0 - mx), e1 = __expf(l1 - mx);
    const float e2 = __expf(l2 - mx), e3 = __expf(l3 - mx);
    float sme = (e0 + e1) + (e2 + e3);
    #pragma unroll
    for (int d = 1; d < 64; d <<= 1) sme += __shfl_xor(sme, d, 64);
    // this wave's j-range [32w, 32w+32) lies in chunk cw = w>>1
    const int cw = w >> 1;
    float evw = (cw == 0) ? e0 : (cw == 1) ? e1 : (cw == 2) ? e2 : e3;
    evw *= 1.f / sme;
    const float attv0 = __shfl(evw, (w & 1)*32 + m,      64);
    const float attv1 = __shfl(evw, (w & 1)*32 + 16 + m, 64);

    #pragma unroll
    for (int mt = 0; mt < 4; ++mt)
        #pragma unroll
        for (int r = 0; r < 4; ++r) {
            acc[mt][0][r] *= attv0;
            acc[mt][1][r] *= attv1;
        }

    // agg partial: einsum over this wave's 32 j
    float p[4][4] = {};
    #pragma unroll
    for (int jt2 = 0; jt2 < 2; ++jt2)
        #pragma unroll
        for (int mt = 0; mt < 4; ++mt) {
            float4 xv = *reinterpret_cast<const float4*>(
                Xjf + (size_t)b*16384 + (size_t)(((w*2 + jt2)*4 + mt)*64 + lane)*4);
            p[mt][0] += acc[mt][jt2][0] * xv.x;
            p[mt][1] += acc[mt][jt2][1] * xv.y;
            p[mt][2] += acc[mt][jt2][2] * xv.z;
            p[mt][3] += acc[mt][jt2][3] * xv.w;
        }
    #pragma unroll
    for (int d = 1; d < 16; d <<= 1)
        #pragma unroll
        for (int mt = 0; mt < 4; ++mt)
            #pragma unroll
            for (int r = 0; r < 4; ++r) p[mt][r] += __shfl_xor(p[mt][r], d, 64);
    if (m == 0) {
        #pragma unroll
        for (int mt = 0; mt < 4; ++mt) {
            float4 st = make_float4(p[mt][0], p[mt][1], p[mt][2], p[mt][3]);
            *reinterpret_cast<float4*>(&agg_lds[w][mt*16 + q*4]) = st;
        }
    }

    // LN stats + bf16 plane store (B-frag layout) + exact t1
    {
        float mean[2], rstd[2];
        #pragma unroll
        for (int jt2 = 0; jt2 < 2; ++jt2) {
            float s = 0.f, ss = 0.f;
            #pragma unroll
            for (int mt = 0; mt < 4; ++mt)
                #pragma unroll
                for (int r = 0; r < 4; ++r) { float vv = acc[mt][jt2][r]; s += vv; ss += vv*vv; }
            s  += __shfl_xor(s, 16, 64);  s  += __shfl_xor(s, 32, 64);
            ss += __shfl_xor(ss, 16, 64); ss += __shfl_xor(ss, 32, 64);
            float mu = s * (1.f/64.f);
            mean[jt2] = mu;
            rstd[jt2] = rsqrtf(ss * (1.f/64.f) - mu*mu + 1e-5f);
        }
        float egv[4][4], ebv[4][4], wcs[4][4];
        #pragma unroll
        for (int mt = 0; mt < 4; ++mt)
            #pragma unroll
            for (int r = 0; r < 4; ++r) {
                const int c = mt*16 + q*4 + r;
                egv[mt][r] = eg[c];
                ebv[mt][r] = eb[c];
                wcs[mt][r] = w41cs[c];
            }
        float* t1g = (float*)(ebase + 32768);
        float t1p[2] = {0.f, 0.f};
        #pragma unroll
        for (int jt2 = 0; jt2 < 2; ++jt2) {
            #pragma unroll
            for (int mt = 0; mt < 4; ++mt) {
                float o[4];
                #pragma unroll
                for (int r = 0; r < 4; ++r) {
                    o[r] = (acc[mt][jt2][r] - mean[jt2]) * rstd[jt2] * egv[mt][r] + ebv[mt][r];
                    t1p[jt2] += o[r] * wcs[mt][r];
                }
                uint2 u2;
                u2.x = ((unsigned int)f2bfbits(o[1]) << 16) | (unsigned int)f2bfbits(o[0]);
                u2.y = ((unsigned int)f2bfbits(o[3]) << 16) | (unsigned int)f2bfbits(o[2]);
                const int qp = (2*mt + (q >> 1)) & 3;
                const size_t addr = (size_t)((((w*2 + jt2)*2 + (mt >> 1))*64 + qp*16 + m))*16 + (q & 1)*8;
                *reinterpret_cast<uint2*>(ebase + addr) = u2;
            }
        }
        #pragma unroll
        for (int jt2 = 0; jt2 < 2; ++jt2) {
            float tv = t1p[jt2];
            tv += __shfl_xor(tv, 16, 64);
            tv += __shfl_xor(tv, 32, 64);
            if (lane < 16) t1g[(w*2 + jt2)*16 + lane] = tv;
        }
    }

    // stage W5[1]/W6[1] for the fused prep tail (all 512 threads, 4 float4s)
    #pragma unroll
    for (int jj = 0; jj < 2; ++jj) {
        const int fidx = jj*2048 + tid*4;
        float4 v5 = *reinterpret_cast<const float4*>(W5l1 + fidx);
        float4 v6 = *reinterpret_cast<const float4*>(W6l1 + fidx);
        const int row = fidx >> 6, col = fidx & 63;
        w5s[row*65+col+0] = v5.x; w5s[row*65+col+1] = v5.y;
        w5s[row*65+col+2] = v5.z; w5s[row*65+col+3] = v5.w;
        w6s[row*65+col+0] = v6.x; w6s[row*65+col+1] = v6.y;
        w6s[row*65+col+2] = v6.z; w6s[row*65+col+3] = v6.w;
    }
    __syncthreads();

    if (w == 0) {
        float a = ((agg_lds[0][lane] + agg_lds[1][lane]) + (agg_lds[2][lane] + agg_lds[3][lane]))
                + ((agg_lds[4][lane] + agg_lds[5][lane]) + (agg_lds[6][lane] + agg_lds[7][lane]));
        float v = fmaxf(a + Xres_ws[(size_t)bi*64 + lane], 0.f);
        float s = v, ss = v*v;
        #pragma unroll
        for (int d = 1; d < 64; d <<= 1) { s += __shfl_xor(s, d, 64); ss += __shfl_xor(ss, d, 64); }
        float mu  = s * (1.f/64.f);
        float var = ss * (1.f/64.f) - mu*mu;
        const float xa = (v - mu) * rsqrtf(var + 1e-5f) * ng[lane] + nb[lane]
                       + Xold[(size_t)bi*64 + lane];
        Xnext[(size_t)bi*64 + lane] = xa;

        // ---- fused layer-1 prep for this row (was prep_kernel<false>) ----
        xrow[lane] = xa;                      // wave-local LDS broadcast buffer
        float aj = 0.f, ar = 0.f;
        #pragma unroll
        for (int k = 0; k < 64; ++k) {
            const float xk = xrow[k];         // broadcast read
            aj += xk * w5s[lane*65 + k];
            ar += xk * w6s[lane*65 + k];
        }
        const int j2 = bi & 255;
        const int wj = j2 >> 6, jt3 = (j2 >> 4) & 3, mm = j2 & 15;
        const int mt3 = lane >> 4, qq = (lane >> 2) & 3, ri = lane & 3;
        Xjf2[(size_t)b*16384 + (size_t)(((wj*4 + jt3)*4 + mt3)*64 + (qq*16 + mm))*4 + ri] = aj;
        Xres2[(size_t)bi*64 + lane] = ar;
        float sv = xa * w3cs[lane];
        #pragma unroll
        for (int d = 1; d < 64; d <<= 1) sv += __shfl_xor(sv, d, 64);
        if (lane == 0) s_ws2[bi] = sv;
    }
}

// ---- layer 1 + head: barrier-free, ONE WAVE per (b,i) (round-0 structure)
//      + 1-chunk-ahead double-buffered prefetch. R8-verbatim (best: 273.4). ----
__global__ __launch_bounds__(256)
void layer1_kernel(const void* __restrict__ Ebuf,
                   const float* __restrict__ s_ws,
                   const float* __restrict__ Xjf,
                   const float* __restrict__ Xres_ws,
                   const float* __restrict__ Xold,
                   const uint4* __restrict__ w4tab,
                   const float* __restrict__ ng,
                   const float* __restrict__ nb,
                   const float* __restrict__ hw1,
                   const float* __restrict__ hb1,
                   const float* __restrict__ hw2,
                   const float* __restrict__ hb2,
                   float* __restrict__ outp)
{
    __shared__ float w1s[64*65];
    __shared__ float w2s[10*65];

    const int tid = threadIdx.x;
    const int w = tid >> 6, lane = tid & 63;
    const int m = lane & 15, q = lane >> 4;

    // stage head weights (one barrier, then waves run free)
    #pragma unroll
    for (int jj = 0; jj < 4; ++jj) {
        const int fidx = jj*1024 + tid*4;
        float4 v = *reinterpret_cast<const float4*>(hw1 + fidx);
        const int row = fidx >> 6, col = fidx & 63;
        w1s[row*65+col+0] = v.x; w1s[row*65+col+1] = v.y;
        w1s[row*65+col+2] = v.z; w1s[row*65+col+3] = v.w;
    }
    if (tid < 160) {
        const int fidx = tid*4;
        float4 v = *reinterpret_cast<const float4*>(hw2 + fidx);
        const int row = fidx >> 6, col = fidx & 63;
        w2s[row*65+col+0] = v.x; w2s[row*65+col+1] = v.y;
        w2s[row*65+col+2] = v.z; w2s[row*65+col+3] = v.w;
    }
    __syncthreads();

    const int bi = blockIdx.x * 4 + w;     // b*256 + i
    const int b  = bi >> 8;
    const char* ebase = (const char*)Ebuf + (size_t)bi * 65536;
    const float* t1g = (const float*)(ebase + 32768);

    // ---- softmax from precomputed t1 (pure wave ops) ----
    float l[4];
    const float si = s_ws[bi];
    #pragma unroll
    for (int c = 0; c < 4; ++c)
        l[c] = t1g[c*64 + lane] + si + s_ws[b*NB + c*64 + lane];
    float mx = fmaxf(fmaxf(l[0], l[1]), fmaxf(l[2], l[3]));
    #pragma unroll
    for (int d = 1; d < 64; d <<= 1) mx = fmaxf(mx, __shfl_xor(mx, d, 64));
    float sme = 0.f;
    #pragma unroll
    for (int c = 0; c < 4; ++c) { l[c] = __expf(l[c] - mx); sme += l[c]; }
    #pragma unroll
    for (int d = 1; d < 64; d <<= 1) sme += __shfl_xor(sme, d, 64);
    const float inv = 1.f / sme;
    #pragma unroll
    for (int c = 0; c < 4; ++c) l[c] *= inv;   // att for j = c*64 + lane

    // A fragments (hi-only), L2-hot
    short8 aH[4][2];
    #pragma unroll
    for (int mt = 0; mt < 4; ++mt) {
        aH[mt][0] = __builtin_bit_cast(short8, w4tab[(mt*4 + 0)*64 + lane]);
        aH[mt][1] = __builtin_bit_cast(short8, w4tab[(mt*4 + 1)*64 + lane]);
    }

    // ---- stream j in 4 chunks of 64, double-buffered (prefetch c+1) ----
    float p[4][4] = {};
    uint4 rb[2][4][2];
    #pragma unroll
    for (int jt = 0; jt < 4; ++jt)
        #pragma unroll
        for (int ks = 0; ks < 2; ++ks)
            rb[0][jt][ks] = *reinterpret_cast<const uint4*>(
                ebase + (size_t)(((0*4 + jt)*2 + ks)*64 + lane) * 16);
    #pragma unroll
    for (int c = 0; c < 4; ++c) {
        const int cur = c & 1, nxt = cur ^ 1;
        if (c < 3) {
            #pragma unroll
            for (int jt = 0; jt < 4; ++jt)
                #pragma unroll
                for (int ks = 0; ks < 2; ++ks)
                    rb[nxt][jt][ks] = *reinterpret_cast<const uint4*>(
                        ebase + (size_t)((((c+1)*4 + jt)*2 + ks)*64 + lane) * 16);
        }
        #pragma unroll
        for (int jt = 0; jt < 4; ++jt) {
            short8 b0 = __builtin_bit_cast(short8, rb[cur][jt][0]);
            short8 b1 = __builtin_bit_cast(short8, rb[cur][jt][1]);
            f4 a0 = {}, a1 = {}, a2 = {}, a3 = {};
            a0 = __builtin_amdgcn_mfma_f32_16x16x32_bf16(aH[0][0], b0, a0, 0, 0, 0);
            a0 = __builtin_amdgcn_mfma_f32_16x16x32_bf16(aH[0][1], b1, a0, 0, 0, 0);
            a1 = __builtin_amdgcn_mfma_f32_16x16x32_bf16(aH[1][0], b0, a1, 0, 0, 0);
            a1 = __builtin_amdgcn_mfma_f32_16x16x32_bf16(aH[1][1], b1, a1, 0, 0, 0);
            a2 = __builtin_amdgcn_mfma_f32_16x16x32_bf16(aH[2][0], b0, a2, 0, 0, 0);
            a2 = __builtin_amdgcn_mfma_f32_16x16x32_bf16(aH[2][1], b1, a2, 0, 0, 0);
            a3 = __builtin_amdgcn_mfma_f32_16x16x32_bf16(aH[3][0], b0, a3, 0, 0, 0);
            a3 = __builtin_amdgcn_mfma_f32_16x16x32_bf16(aH[3][1], b1, a3, 0, 0, 0);
            const float av = __shfl(l[c], jt*16 + m, 64);
            const float* xb = Xjf + (size_t)b*16384 + (size_t)(((c*4 + jt)*4)*64 + lane)*4;
            float4 x0 = *reinterpret_cast<const float4*>(xb);
            float4 x1 = *reinterpret_cast<const float4*>(xb + 256);
            float4 x2 = *reinterpret_cast<const float4*>(xb + 512);
            float4 x3 = *reinterpret_cast<const float4*>(xb + 768);
            p[0][0] += a0[0]*av*x0.x; p[0][1] += a0[1]*av*x0.y;
            p[0][2] += a0[2]*av*x0.z; p[0][3] += a0[3]*av*x0.w;
            p[1][0] += a1[0]*av*x1.x; p[1][1] += a1[1]*av*x1.y;
            p[1][2] += a1[2]*av*x1.z; p[1][3] += a1[3]*av*x1.w;
            p[2][0] += a2[0]*av*x2.x; p[2][1] += a2[1]*av*x2.y;
            p[2][2] += a2[2]*av*x2.z; p[2][3] += a2[3]*av*x2.w;
            p[3][0] += a3[0]*av*x3.x; p[3][1] += a3[1]*av*x3.y;
            p[3][2] += a3[2]*av*x3.z; p[3][3] += a3[3]*av*x3.w;
        }
    }

    // butterfly-reduce over the 16 m-lanes: all lanes end with agg for
    // h = mt*16 + q*4 + r (q = lane>>4)
    #pragma unroll
    for (int d = 1; d < 16; d <<= 1)
        #pragma unroll
        for (int mt = 0; mt < 4; ++mt)
            #pragma unroll
            for (int r = 0; r < 4; ++r) p[mt][r] += __shfl_xor(p[mt][r], d, 64);

    // per-wave X-update: v = relu(agg + Xres), LN over h, + Xold
    float4 xres[4], xold[4], ngv[4], nbv[4];
    #pragma unroll
    for (int mt = 0; mt < 4; ++mt) {
        const int hb = mt*16 + q*4;
        xres[mt] = *reinterpret_cast<const float4*>(Xres_ws + (size_t)bi*64 + hb);
        xold[mt] = *reinterpret_cast<const float4*>(Xold    + (size_t)bi*64 + hb);
        ngv[mt]  = *reinterpret_cast<const float4*>(ng + hb);
        nbv[mt]  = *reinterpret_cast<const float4*>(nb + hb);
    }
    float v[4][4];
    float s = 0.f, ss = 0.f;
    #pragma unroll
    for (int mt = 0; mt < 4; ++mt) {
        v[mt][0] = fmaxf(p[mt][0] + xres[mt].x, 0.f);
        v[mt][1] = fmaxf(p[mt][1] + xres[mt].y, 0.f);
        v[mt][2] = fmaxf(p[mt][2] + xres[mt].z, 0.f);
        v[mt][3] = fmaxf(p[mt][3] + xres[mt].w, 0.f);
        #pragma unroll
        for (int r = 0; r < 4; ++r) { s += v[mt][r]; ss += v[mt][r]*v[mt][r]; }
    }
    s  += __shfl_xor(s, 16, 64);  s  += __shfl_xor(s, 32, 64);
    ss += __shfl_xor(ss, 16, 64); ss += __shfl_xor(ss, 32, 64);
    const float mu   = s * (1.f/64.f);
    const float rstd = rsqrtf(ss * (1.f/64.f) - mu*mu + 1e-5f);
    float xf[4][4];
    #pragma unroll
    for (int mt = 0; mt < 4; ++mt) {
        xf[mt][0] = (v[mt][0] - mu) * rstd * ngv[mt].x + nbv[mt].x + xold[mt].x;
        xf[mt][1] = (v[mt][1] - mu) * rstd * ngv[mt].y + nbv[mt].y + xold[mt].y;
        xf[mt][2] = (v[mt][2] - mu) * rstd * ngv[mt].z + nbv[mt].z + xold[mt].z;
        xf[mt][3] = (v[mt][3] - mu) * rstd * ngv[mt].w + nbv[mt].w + xold[mt].w;
    }

    // ---- fused head (per-wave, X broadcast via shuffles) ----
    float h1 = hb1[lane];
    #pragma unroll
    for (int mt = 0; mt < 4; ++mt)
        #pragma unroll
        for (int q2 = 0; q2 < 4; ++q2)
            #pragma unroll
            for (int r = 0; r < 4; ++r) {
                const float xv = __shfl(xf[mt][r], q2*16, 64);
                h1 += xv * w1s[lane*65 + mt*16 + q2*4 + r];
            }
    h1 = fmaxf(h1, 0.f);
    float pa[10];
    #pragma unroll
    for (int a = 0; a < 10; ++a) pa[a] = h1 * w2s[a*65 + lane];
    #pragma unroll
    for (int d = 1; d < 64; d <<= 1)
        #pragma unroll
        for (int a = 0; a < 10; ++a) pa[a] += __shfl_xor(pa[a], d, 64);
    if (lane == 0) {
        #pragma unroll
        for (int a = 0; a < 10; ++a) outp[(size_t)bi*10 + a] = pa[a] + hb2[a];
    }
}

extern "C" void kernel_launch(void* const* d_in, const int* in_sizes, int n_in,
                              void* d_out, int out_size, void* d_ws, size_t ws_size,
                              hipStream_t stream) {
    const float* X   = (const float*)d_in[0];
    void*        E   = (void*)d_in[1];           // f32 in; bf16 plane + t1 written in place
    const float* W3  = (const float*)d_in[2];
    const float* W4  = (const float*)d_in[3];
    const float* W5  = (const float*)d_in[4];
    const float* W6  = (const float*)d_in[5];
    const float* ng  = (const float*)d_in[6];
    const float* nbp = (const float*)d_in[7];
    const float* eg  = (const float*)d_in[8];
    const float* ebp = (const float*)d_in[9];
    const float* hw1 = (const float*)d_in[10];
    const float* hb1 = (const float*)d_in[11];
    const float* hw2 = (const float*)d_in[12];
    const float* hb2 = (const float*)d_in[13];
    float* outp = (float*)d_out;

    float* wsf   = (float*)d_ws;
    float* s_ws  = wsf;                    // 2048
    float* Xjf   = wsf + 2048;             // 131072
    float* Xres  = wsf + 133120;           // 131072
    float* Xa    = wsf + 264192;           // 131072
    float* w41cs = wsf + 395264;           // 64
    float* w3cs  = wsf + 395328;           // 64
    uint4* w4tab = (uint4*)(wsf + 395392); // 2048 uint4 (32 KB) -> ends 403584
    float* s2    = wsf + 403584;           // 2048
    float* Xjf2  = wsf + 405632;           // 131072
    float* Xres2 = wsf + 536704;           // 131072

    // prep (layer-0 rows; blocks 512/513 build W4 tables + colsums)
    prep_kernel<<<514, 256, 0, stream>>>(X, W3, W5, W6, W4, w4tab, w41cs,
        W3 + 4096, w3cs, s_ws, Xjf, Xres);
    // layer 0 with fused layer-1 prep tail (prep2 kernel eliminated)
    layer0_kernel<<<2048, 512, 0, stream>>>(E, s_ws, Xjf, Xres,
        X, Xa, w4tab, w41cs, eg, ebp, ng, nbp,
        W5 + 4096, W6 + 4096, w3cs, s2, Xjf2, Xres2);
    // layer 1 + fused head
    layer1_kernel<<<512, 256, 0, stream>>>(E, s2, Xjf2, Xres2,
        Xa, w4tab + 1024, ng + 64, nbp + 64, hw1, hb1, hw2, hb2, outp);
}